// Round 8
// baseline (184.686 us; speedup 1.0000x reference)
//
#include <hip/hip_runtime.h>

typedef unsigned int  u32;
typedef unsigned short u16;

typedef __bf16 bf16x8 __attribute__((ext_vector_type(8)));
typedef float  floatx4 __attribute__((ext_vector_type(4)));

#define N_ROWS 256
#define IN_F   8192
#define OUT_F  8320
#define JDIM   128
#define KDIM   16
#define JK     2048

#define NSLAB  16
#define GKSL   512           // k per gemm slab (IN_F/NSLAB)
#define TC     512           // transpose tile cols
#define TK     64            // transpose tile k-rows
#define LP     264           // LDS u32 row stride (TC/2 + 8 pad)

__device__ __forceinline__ u16 f2bf(float f) {
    u32 u = __float_as_uint(f);
    return (u16)((u + 0x7fffu + ((u >> 16) & 1u)) >> 16);
}
__device__ __forceinline__ float bf2f(u16 h) { return __uint_as_float(((u32)h) << 16); }

// Kernel A: copy X into out[:, :8192], cvt X->bf16 into Xb, zero diversity region of out.
__global__ __launch_bounds__(256) void prep_kernel(const float* __restrict__ X,
                                                   float* __restrict__ out,
                                                   u16* __restrict__ Xb)
{
    int t = blockIdx.x * 256 + threadIdx.x;      // 0..524287, one float4 each
    float4 v = reinterpret_cast<const float4*>(X)[t];
    int row = t >> 11;
    int c4  = t & 2047;
    reinterpret_cast<float4*>(out + (size_t)row * OUT_F)[c4] = v;
    ushort4 b;
    b.x = f2bf(v.x); b.y = f2bf(v.y); b.z = f2bf(v.z); b.w = f2bf(v.w);
    reinterpret_cast<ushort4*>(Xb)[t] = b;
    if (t < 8192) {
        int r2 = t >> 5, j4 = t & 31;
        reinterpret_cast<float4*>(out + (size_t)r2 * OUT_F + IN_F)[j4] = make_float4(0.f, 0.f, 0.f, 0.f);
    }
}

// Kernel B: Tbt[c][k] = bf16(T[k][c]) -- pure streaming transpose+cvt.
// Tile 64k x 512c: reads 1KB contiguous per wave-instr; LDS u32 [r][cpair] (pad 264);
// out: thread owns col pair (2t,2t+1): 64 conflict-free ds_read_b32 + v_perm-style
// repack -> 2 x 128B contiguous global writes. 64MB read + 32MB write, sequential.
__global__ __launch_bounds__(256) void transpose_kernel(const float* __restrict__ T,
                                                        u16* __restrict__ Tbt)
{
    __shared__ u32 L[TK * LP];          // 67.6 KB -> 2 blocks/CU

    const int t  = threadIdx.x;
    const int c0 = blockIdx.x * TC;     // 0..3
    const int k0 = blockIdx.y * TK;     // 0..127

    const int c4 = t & 127;             // float4 col unit within tile
    const int rh = t >> 7;              // row half (0/1)

    #pragma unroll
    for (int i = 0; i < 32; ++i) {
        int r = rh * 32 + i;
        float4 v = *(const float4*)(T + (size_t)(k0 + r) * JK + c0 + c4 * 4);
        uint2 pk;
        pk.x = (u32)f2bf(v.x) | ((u32)f2bf(v.y) << 16);   // cols c4*4, c4*4+1
        pk.y = (u32)f2bf(v.z) | ((u32)f2bf(v.w) << 16);   // cols c4*4+2, +3
        *(uint2*)&L[r * LP + c4 * 2] = pk;
    }
    __syncthreads();

    // col pair (2t, 2t+1): L[r][t] = {c=2t lo, c=2t+1 hi}
    u32 oe[32], oo[32];
    #pragma unroll
    for (int kp = 0; kp < 32; ++kp) {
        u32 a = L[(2 * kp) * LP + t];
        u32 b = L[(2 * kp + 1) * LP + t];
        oe[kp] = (a & 0xffffu) | (b << 16);          // k=2kp, 2kp+1 of col 2t
        oo[kp] = (a >> 16) | (b & 0xffff0000u);      // k=2kp, 2kp+1 of col 2t+1
    }
    u16* o0 = Tbt + (size_t)(c0 + 2 * t) * IN_F + k0;
    u16* o1 = o0 + IN_F;
    #pragma unroll
    for (int j = 0; j < 8; ++j) {
        *(uint4*)(o0 + j * 8) = *(uint4*)&oe[j * 4];
        *(uint4*)(o1 + j * 8) = *(uint4*)&oo[j * 4];
    }
}

// Kernel C: slab[s] = Xb[256r, 512k] * Tbt[2048c, 512k]^T. ZERO LDS/barriers/packing.
// Both operands row-major-in-k bf16 -> every frag is a direct 16B b128 load; a quad
// (fixed n, q=0..3) covers 64B of one row = full line. Operands L2/L3-served.
// Block 256 thr = 4 waves (2r x 2c), tile 128r x 64c. Grid (32, 2, 16) = 1024 blocks.
__global__ __launch_bounds__(256) void gemm_kernel(const u16* __restrict__ Xb,
                                                   const u16* __restrict__ Tbt,
                                                   u16* __restrict__ slabs)
{
    const int tid  = threadIdx.x;
    const int lane = tid & 63;
    const int w    = tid >> 6;
    const int c0   = blockIdx.x * 64;
    const int m0   = blockIdx.y * 128;
    const int s    = blockIdx.z;
    const int k0   = s * GKSL;

    const int n = lane & 15, q = lane >> 4;
    const int wr0 = m0 + (w & 1) * 64;
    const int wc0 = c0 + (w >> 1) * 32;

    floatx4 acc[4][2] = {};

    const u16* arow[4];
    const u16* brow[2];
    #pragma unroll
    for (int rf = 0; rf < 4; ++rf)
        arow[rf] = Xb + (size_t)(wr0 + rf * 16 + n) * IN_F + k0 + q * 8;
    #pragma unroll
    for (int cf = 0; cf < 2; ++cf)
        brow[cf] = Tbt + (size_t)(wc0 + cf * 16 + n) * IN_F + k0 + q * 8;

    bf16x8 a[4], b[2], an[4], bn[2];
    #pragma unroll
    for (int rf = 0; rf < 4; ++rf) a[rf] = *(const bf16x8*)(arow[rf]);
    #pragma unroll
    for (int cf = 0; cf < 2; ++cf) b[cf] = *(const bf16x8*)(brow[cf]);

    const int KC = GKSL / 32;            // 16
    for (int kc = 0; kc < KC; ++kc) {
        if (kc + 1 < KC) {
            #pragma unroll
            for (int rf = 0; rf < 4; ++rf) an[rf] = *(const bf16x8*)(arow[rf] + (kc + 1) * 32);
            #pragma unroll
            for (int cf = 0; cf < 2; ++cf) bn[cf] = *(const bf16x8*)(brow[cf] + (kc + 1) * 32);
        }
        #pragma unroll
        for (int rf = 0; rf < 4; ++rf)
            #pragma unroll
            for (int cf = 0; cf < 2; ++cf)
                acc[rf][cf] = __builtin_amdgcn_mfma_f32_16x16x32_bf16(a[rf], b[cf], acc[rf][cf], 0, 0, 0);
        #pragma unroll
        for (int rf = 0; rf < 4; ++rf) a[rf] = an[rf];
        #pragma unroll
        for (int cf = 0; cf < 2; ++cf) b[cf] = bn[cf];
    }

    // epilogue: bf16 stores. D: col=lane&15, row=(lane>>4)*4+reg
    u16* sp = slabs + (size_t)s * N_ROWS * JK;
    #pragma unroll
    for (int rf = 0; rf < 4; ++rf)
        #pragma unroll
        for (int cf = 0; cf < 2; ++cf)
            #pragma unroll
            for (int rr = 0; rr < 4; ++rr) {
                int row = wr0 + rf * 16 + q * 4 + rr;
                int col = wc0 + cf * 16 + n;
                sp[(size_t)row * JK + col] = f2bf(acc[rf][cf][rr]);
            }
}

// Kernel D: feats[n,jk] = sum_s slab[s][n,jk] (bf16 -> fp32).
__global__ __launch_bounds__(256) void reduce_kernel(const u16* __restrict__ slabs,
                                                     float* __restrict__ feats)
{
    int t = blockIdx.x * 256 + threadIdx.x;      // 65536 threads x 8 elems
    float acc[8] = {};
    for (int s = 0; s < NSLAB; ++s) {
        uint4 v = *(const uint4*)(slabs + (size_t)s * N_ROWS * JK + (size_t)t * 8);
        const u16* h = (const u16*)&v;
        #pragma unroll
        for (int e = 0; e < 8; ++e) acc[e] += bf2f(h[e]);
    }
    float4* fp = (float4*)(feats + (size_t)t * 8);
    fp[0] = make_float4(acc[0], acc[1], acc[2], acc[3]);
    fp[1] = make_float4(acc[4], acc[5], acc[6], acc[7]);
}

// Kernel E: diversity[n,j] = sum_m exp(-sum_k |feats[n,j,k]-feats[m,j,k]|), m-chunked.
__global__ __launch_bounds__(256) void pairwise_kernel(const float* __restrict__ feats,
                                                       float* __restrict__ out)
{
    const int j = blockIdx.x;              // 0..127
    const int mq = blockIdx.y;             // 0..3 -> m chunk of 64
    const int n = threadIdx.x;

    __shared__ float F[N_ROWS * KDIM];     // 16 KB
    const float* fr = feats + (size_t)n * JK + j * KDIM;
    float4 v0 = ((const float4*)fr)[0];
    float4 v1 = ((const float4*)fr)[1];
    float4 v2 = ((const float4*)fr)[2];
    float4 v3 = ((const float4*)fr)[3];
    float4* Fp = (float4*)&F[n * KDIM];
    Fp[0] = v0; Fp[1] = v1; Fp[2] = v2; Fp[3] = v3;
    __syncthreads();

    float f[16] = { v0.x, v0.y, v0.z, v0.w, v1.x, v1.y, v1.z, v1.w,
                    v2.x, v2.y, v2.z, v2.w, v3.x, v3.y, v3.z, v3.w };
    float accum = 0.f;
    const int m0 = mq * 64;
    for (int m = 0; m < 64; ++m) {
        const float* Fm = &F[(m0 + m) * KDIM];   // wave-uniform -> LDS broadcast
        float l1 = 0.f;
        #pragma unroll
        for (int k = 0; k < 16; ++k) l1 += fabsf(f[k] - Fm[k]);
        accum += exp2f(-1.4426950408889634f * l1);
    }
    atomicAdd(&out[(size_t)n * OUT_F + IN_F + j], accum);
}

extern "C" void kernel_launch(void* const* d_in, const int* in_sizes, int n_in,
                              void* d_out, int out_size, void* d_ws, size_t ws_size,
                              hipStream_t stream)
{
    const float* X = (const float*)d_in[0];   // [256, 8192] fp32
    const float* T = (const float*)d_in[1];   // [8192, 128, 16] fp32 = [8192, 2048]
    float* out = (float*)d_out;               // [256, 8320] fp32

    float* feats = (float*)d_ws;                            // 2 MB fp32 [256,2048]
    u16*   Xb    = (u16*)((char*)d_ws + (2u << 20));        // 4 MB bf16 [256,8192]
    u16*   slabs = (u16*)((char*)d_ws + (6u << 20));        // 16 MB bf16 [16,256,2048]
    u16*   Tbt   = (u16*)((char*)d_ws + (22u << 20));       // 32 MB bf16 [2048,8192]

    prep_kernel<<<2048, 256, 0, stream>>>(X, out, Xb);
    transpose_kernel<<<dim3(JK / TC, IN_F / TK), 256, 0, stream>>>(T, Tbt);
    gemm_kernel<<<dim3(JK / 64, N_ROWS / 128, NSLAB), 256, 0, stream>>>(Xb, Tbt, slabs);
    reduce_kernel<<<256, 256, 0, stream>>>(slabs, feats);
    pairwise_kernel<<<dim3(JDIM, 4), 256, 0, stream>>>(feats, out);
}